// Round 1
// baseline (124.443 us; speedup 1.0000x reference)
//
#include <hip/hip_runtime.h>

// Problem constants (fixed by setup_inputs)
#define NB 16
#define NS 8
#define NPTS 131072
#define NA 18
#define CHUNKS 16
#define ELEMS (NPTS / CHUNKS)          // 8192 per block
#define THREADS 256
#define GROUPS (ELEMS / 4 / THREADS)   // 8 float4 groups per thread

// ws layout (floats): Sp[16][8][8] (binned logit sums), T[16][8], sums[2]
#define WS_SP 0
#define WS_T  (NB * NS * NS)           // 1024
#define WS_SUMS (WS_T + NB * NS)       // 1152
#define WS_FLOATS (WS_SUMS + 2)        // 1154

__device__ __forceinline__ void proc_elem(float x, int m, float acc[8], float& tsum) {
    // x = log(p); reference: lgp = max(x, -100), lg1m = max(log1p(-exp(x)), -100)
    float lgp  = fmaxf(x, -100.0f);
    float e    = __expf(x);                      // p in (1e-4, 1-1e-4) by construction
    float lg1m = fmaxf(__logf(1.0f - e), -100.0f);
    float d    = lgp - lg1m;                     // logit contribution for the matched bin
    tsum += lg1m;
#pragma unroll
    for (int j = 0; j < 8; ++j) acc[j] += (m == j) ? d : 0.0f;
}

__global__ __launch_bounds__(THREADS) void seg_accum_kernel(
    const float* __restrict__ logp, const int* __restrict__ mask,
    float* __restrict__ ws) {
    const int chunk = blockIdx.x;
    const int i = blockIdx.y;
    const int b = blockIdx.z;
    const size_t roff = ((size_t)(b * NS + i)) * NPTS + (size_t)chunk * ELEMS;
    const float4* lp4 = (const float4*)(logp + roff);
    const int4*   m4  = (const int4*)(mask + (size_t)b * NPTS + (size_t)chunk * ELEMS);

    float acc[8] = {0.f, 0.f, 0.f, 0.f, 0.f, 0.f, 0.f, 0.f};
    float tsum = 0.f;

#pragma unroll
    for (int g = 0; g < GROUPS; ++g) {
        const int idx = g * THREADS + (int)threadIdx.x;
        const float4 lp = lp4[idx];
        const int4   mm = m4[idx];
        proc_elem(lp.x, mm.x, acc, tsum);
        proc_elem(lp.y, mm.y, acc, tsum);
        proc_elem(lp.z, mm.z, acc, tsum);
        proc_elem(lp.w, mm.w, acc, tsum);
    }

    // wave (64-lane) shuffle reduction
#pragma unroll
    for (int off = 32; off > 0; off >>= 1) {
#pragma unroll
        for (int j = 0; j < 8; ++j) acc[j] += __shfl_down(acc[j], off);
        tsum += __shfl_down(tsum, off);
    }

    __shared__ float red[THREADS / 64][9];
    const int wave = threadIdx.x >> 6;
    const int lane = threadIdx.x & 63;
    if (lane == 0) {
#pragma unroll
        for (int j = 0; j < 8; ++j) red[wave][j] = acc[j];
        red[wave][8] = tsum;
    }
    __syncthreads();
    if (threadIdx.x < 9) {
        float v = red[0][threadIdx.x] + red[1][threadIdx.x] +
                  red[2][threadIdx.x] + red[3][threadIdx.x];
        if (threadIdx.x < 8)
            atomicAdd(&ws[WS_SP + ((b * NS + i) * NS) + threadIdx.x], v);
        else
            atomicAdd(&ws[WS_T + b * NS + i], v);
    }
}

// 32 blocks (b, which) x 64 threads: build 8x8 cost matrix, assignment DP, accumulate mean
__global__ __launch_bounds__(64) void assign_kernel(
    const float* __restrict__ ws_in, const float* __restrict__ pred_aff,
    const int* __restrict__ gt_aff, float* __restrict__ sums) {
    const int bw = blockIdx.x;
    const int b = bw >> 1;
    const int w = bw & 1;          // 0 = seg, 1 = aff
    const int lane = threadIdx.x;  // 64 threads = 1 wave
    const int i = lane >> 3, j = lane & 7;

    __shared__ float cost[8][8];
    __shared__ float dp[256];

    float c;
    if (w == 0) {
        c = -(ws_in[WS_SP + ((b * NS + i) * NS) + j] + ws_in[WS_T + b * NS + i]) *
            (1.0f / (float)NPTS);
    } else {
        float a = 0.f;
#pragma unroll
        for (int k = 0; k < NA; ++k) {
            float p = pred_aff[((b * NS + i) * NA) + k];
            float g = (float)gt_aff[((b * NS + j) * NA) + k];
            float lgp  = fmaxf(__logf(p), -100.0f);
            float l1m  = fmaxf(__logf(1.0f - p), -100.0f);
            a += g * lgp + (1.0f - g) * l1m;
        }
        c = -a * (1.0f / (float)NA);
    }
    cost[i][j] = c;

    dp[lane] = 1e30f; dp[lane + 64] = 1e30f; dp[lane + 128] = 1e30f; dp[lane + 192] = 1e30f;
    __syncthreads();
    if (lane == 0) dp[0] = 0.f;
    __syncthreads();

    // dp[mask] = min cost assigning rows 0..popc(mask)-1 to column set `mask`
    for (int l = 1; l <= 8; ++l) {
#pragma unroll
        for (int base = 0; base < 256; base += 64) {
            const int mm = base + lane;
            if (__popc(mm) == l) {
                float best = 1e30f;
#pragma unroll
                for (int jj = 0; jj < 8; ++jj) {
                    if (mm & (1 << jj))
                        best = fminf(best, dp[mm ^ (1 << jj)] + cost[l - 1][jj]);
                }
                dp[mm] = best;
            }
        }
        __syncthreads();
    }
    if (lane == 0) atomicAdd(&sums[w], dp[255] * (1.0f / (float)NB));
}

__global__ void writeout_kernel(const float* __restrict__ sums, float* __restrict__ out) {
    const float seg = sums[0], aff = sums[1];
    out[0] = seg;
    out[1] = aff;
    out[2] = aff + 3.0f * seg;
}

extern "C" void kernel_launch(void* const* d_in, const int* in_sizes, int n_in,
                              void* d_out, int out_size, void* d_ws, size_t ws_size,
                              hipStream_t stream) {
    const float* pred_seg_logp = (const float*)d_in[0];
    const float* pred_aff      = (const float*)d_in[1];
    const int*   gt_seg_mask   = (const int*)d_in[2];
    const int*   gt_aff        = (const int*)d_in[3];
    float* out = (float*)d_out;
    float* ws  = (float*)d_ws;

    hipMemsetAsync(ws, 0, WS_FLOATS * sizeof(float), stream);

    dim3 grid(CHUNKS, NS, NB);
    seg_accum_kernel<<<grid, THREADS, 0, stream>>>(pred_seg_logp, gt_seg_mask, ws);
    assign_kernel<<<NB * 2, 64, 0, stream>>>(ws, pred_aff, gt_aff, ws + WS_SUMS);
    writeout_kernel<<<1, 1, 0, stream>>>(ws + WS_SUMS, out);
}